// Round 8
// baseline (621.775 us; speedup 1.0000x reference)
//
#include <hip/hip_runtime.h>
#include <math.h>

#define BB 8
#define CC 96
#define HH 256
#define WW 256
#define HW (HH*WW)
#define NBLK 1024

typedef unsigned long long u64;
typedef float f32x4 __attribute__((ext_vector_type(4)));
typedef u64 u64x2 __attribute__((ext_vector_type(2)));

// device-scope grid barrier; cnt/flag zeroed by hipMemsetAsync each launch
__device__ __forceinline__ void gbar(unsigned* cnt, unsigned* flag) {
    __syncthreads();
    if (threadIdx.x == 0) {
        __threadfence();
        unsigned v = atomicAdd(cnt, 1u);
        if (v == NBLK - 1u) {
            __threadfence();
            atomicExch(flag, 1u);
        } else {
            while (atomicAdd(flag, 0u) == 0u) { __builtin_amdgcn_s_sleep(2); }
        }
        __threadfence();
    }
    __syncthreads();
}

#define SETBIT(j) do { int _j = (j); \
    if (_j < 64) m0 |= 1ull << _j; \
    else if (_j < 128) m1 |= 1ull << (_j - 64); \
    else if (_j < 192) m2 |= 1ull << (_j - 128); \
    else m3 |= 1ull << (_j - 192); } while (0)

// ---- fused: mean -> bar -> sobel/minmax -> bar -> adjpart -> bar -> travbase(blocks<32) ----
__global__ __launch_bounds__(256, 4)
void k_fused(const float* __restrict__ x, float* __restrict__ m, float* __restrict__ mag,
             signed char* __restrict__ adj, float* __restrict__ part,
             u64* __restrict__ masks, u64* __restrict__ colm,
             unsigned* __restrict__ mn_u, unsigned* __restrict__ mx_u,
             unsigned* __restrict__ bar) {
    __shared__ double sbuf[4][4][64];     // P1 (8 KB)
    __shared__ float s4[4];               // P3
    __shared__ double sd[128];            // P4 (1 KB)
    __shared__ int sbs;                   // P4

    int tid = threadIdx.x, wv = tid >> 6, ln = tid & 63;

    if (blockIdx.x == 0 && tid < 2 * BB) {
        if (tid < BB) mn_u[tid] = 0x7f800000u;
        else          mx_u[tid - BB] = 0u;
    }

    // ---------------- P1: channel mean (identical f64 accumulation) ----------------
    for (int u = blockIdx.x; u < BB * 256; u += NBLK) {
        int b = u >> 8, tile = u & 255;
        int hw4 = tile * 64 + ln;
        const int per = HW / 4;           // 16384
        const float4* xb = reinterpret_cast<const float4*>(x)
                         + ((size_t)b * CC + wv * 24) * per + hw4;
        double a0 = 0, a1 = 0, a2 = 0, a3 = 0;
#pragma unroll
        for (int c = 0; c < 24; ++c) {
            float4 v = xb[(size_t)c * per];
            a0 += (double)v.x; a1 += (double)v.y; a2 += (double)v.z; a3 += (double)v.w;
        }
        __syncthreads();                  // protect sbuf reuse across u-iterations
        sbuf[wv][0][ln] = a0; sbuf[wv][1][ln] = a1;
        sbuf[wv][2][ln] = a2; sbuf[wv][3][ln] = a3;
        __syncthreads();
        if (wv == 0) {
            double r0 = sbuf[0][0][ln] + sbuf[1][0][ln] + sbuf[2][0][ln] + sbuf[3][0][ln];
            double r1 = sbuf[0][1][ln] + sbuf[1][1][ln] + sbuf[2][1][ln] + sbuf[3][1][ln];
            double r2 = sbuf[0][2][ln] + sbuf[1][2][ln] + sbuf[2][2][ln] + sbuf[3][2][ln];
            double r3 = sbuf[0][3][ln] + sbuf[1][3][ln] + sbuf[2][3][ln] + sbuf[3][3][ln];
            float4 o;
            o.x = (float)(r0 / 96.0); o.y = (float)(r1 / 96.0);
            o.z = (float)(r2 / 96.0); o.w = (float)(r3 / 96.0);
            reinterpret_cast<float4*>(m)[(size_t)b * per + hw4] = o;
        }
    }
    gbar(bar + 0, bar + 1);

    // ---------------- P2: sobel magnitude + per-image min/max ----------------
    for (int u = blockIdx.x; u < BB * HH; u += NBLK) {
        int b = u >> 8, h = u & 255, w = tid;
        const float* mb = m + (size_t)b * HW;
        auto at = [&](int hh, int ww) -> float {
            if (hh < 0 || hh >= HH || ww < 0 || ww >= WW) return 0.0f;
            return mb[hh * WW + ww];
        };
        float a00 = at(h - 1, w - 1), a01 = at(h - 1, w), a02 = at(h - 1, w + 1);
        float a10 = at(h, w - 1),                         a12 = at(h, w + 1);
        float a20 = at(h + 1, w - 1), a21 = at(h + 1, w), a22 = at(h + 1, w + 1);
        float gx = a00 - a02 + 2.0f * a10 - 2.0f * a12 + a20 - a22;
        float gy = a00 + 2.0f * a01 + a02 - a20 - 2.0f * a21 - a22;
        float mg = sqrtf(gx * gx + gy * gy + 1e-6f);
        mag[u * WW + w] = mg;

        float lmn = mg, lmx = mg;
        for (int off = 32; off; off >>= 1) {
            lmn = fminf(lmn, __shfl_down(lmn, off));
            lmx = fmaxf(lmx, __shfl_down(lmx, off));
        }
        if (ln == 0) {                    // min/max is order-free -> per-wave atomic is exact
            atomicMin(&mn_u[b], __float_as_uint(lmn));
            atomicMax(&mx_u[b], __float_as_uint(lmx));
        }
    }
    gbar(bar + 2, bar + 3);

    // ---------------- P3: normalize (recompute) -> adj + part ----------------
    for (int u = blockIdx.x; u < BB * HH; u += NBLK) {
        int b = u >> 8, h = u & 255, w = tid;
        float mn = __uint_as_float(mn_u[b]);
        float mx = __uint_as_float(mx_u[b]);
        float rng = mx - mn;
        const float* gb = mag + (size_t)b * HW;
        auto cat = [&](int hh, int ww) -> float {
            if (hh < 0 || hh >= HH || ww < 0 || ww >= WW) return 0.0f;
            float mg = gb[hh * WW + ww];
            return (rng > 0.0f) ? (mg - mn) / (rng + 1e-6f) : 0.0f;
        };
        float cc = cat(h, w);

        float r = cc;
        for (int off = 32; off; off >>= 1) r += __shfl_down(r, off);
        __syncthreads();                  // protect s4 reuse across u-iterations
        if (ln == 0) s4[wv] = r;
        __syncthreads();
        if (tid == 0) {
            part[u * 2 + 0] = s4[0] + s4[1];   // w in [0,128)
            part[u * 2 + 1] = s4[2] + s4[3];   // w in [128,256)
        }

        const float w9 = 1.0f / 9.0f;
        float acc = 0.0f;
        acc = fmaf(cat(h - 1, w - 1), w9, acc);
        acc = fmaf(cat(h - 1, w    ), w9, acc);
        acc = fmaf(cat(h - 1, w + 1), w9, acc);
        acc = fmaf(cat(h    , w - 1), w9, acc);
        acc = fmaf(cc,               w9, acc);
        acc = fmaf(cat(h    , w + 1), w9, acc);
        acc = fmaf(cat(h + 1, w - 1), w9, acc);
        acc = fmaf(cat(h + 1, w    ), w9, acc);
        acc = fmaf(cat(h + 1, w + 1), w9, acc);
        float sg = 1.0f / (1.0f + expf(-5.0f * (acc - 0.5f)));
        adj[u * WW + w] = (signed char)(int)rintf(sg * 2.0f - 1.0f);
    }
    gbar(bar + 4, bar + 5);

    // ---------------- P4: base + traversal (blocks 0..31 only) ----------------
    if (blockIdx.x < 32) {
        int dir = blockIdx.x >> 3, b = blockIdx.x & 7;
        int t = tid;
        int hlo = (dir >> 1) ? 128 : 0;
        int col = dir & 1;
        if (t < 128) sd[t] = (double)part[((b << 8) + hlo + t) * 2 + col];
        __syncthreads();
        for (int str = 64; str > 0; str >>= 1) {
            if (t < str) sd[t] += sd[t + str];
            __syncthreads();
        }
        if (t == 0) {
            float rc = (float)(sd[0] / 16384.0);
            float sig = 1.0f / (1.0f + expf(-5.0f * (rc - 0.5f)));
            float bsf = 5.0f - sig * 4.0f;
            bsf = fminf(fmaxf(bsf, 1.0f), 5.0f);
            sbs = (int)rintf(bsf);
        }
        __syncthreads();
        int bs = sbs;

        int r = t;
        const signed char* ab = adj + (size_t)b * HW;
        u64 m0 = 0, m1 = 0, m2 = 0, m3 = 0;
        if (dir == 0) {
            int j = 0;
            while (j < WW) { SETBIT(j);
                int st = bs + (int)ab[r * WW + j];
                st = st < 1 ? 1 : (st > 5 ? 5 : st); j += st; }
        } else if (dir == 1) {
            int j = WW - 1;
            while (j >= 0) { SETBIT(j);
                int st = bs + (int)ab[r * WW + j];
                st = st < 1 ? 1 : (st > 5 ? 5 : st); j -= st; }
        } else if (dir == 2) {
            int j = 0;
            while (j < HH) { SETBIT(j);
                int st = bs + (int)ab[j * WW + r];
                st = st < 1 ? 1 : (st > 5 ? 5 : st); j += st; }
        } else {
            int j = HH - 1;
            while (j >= 0) { SETBIT(j);
                int st = bs + (int)ab[j * WW + r];
                st = st < 1 ? 1 : (st > 5 ? 5 : st); j -= st; }
        }
        if (dir < 2) {
            u64* o = masks + (((size_t)dir * BB + b) * 256 + r) * 4;
            o[0] = m0; o[1] = m1; o[2] = m2; o[3] = m3;
        } else {
            u64* ct = colm + (((size_t)(dir - 2) * BB + b) * 4) * 256 + r;
            ct[0 * 256] = m0; ct[1 * 256] = m1; ct[2 * 256] = m2; ct[3 * 256] = m3;
        }
    }
}

// ---------------- output: out = x * V/(V+eps), all mask reads coalesced ----------------
__global__ void k_out(const float* __restrict__ x, const u64* __restrict__ masks,
                      const u64* __restrict__ colm, float* __restrict__ out) {
    const int per_img4 = CC * HW / 4;     // 1572864
    const int hw4n = HW / 4;              // 16384 (pow2)
    int i = blockIdx.x * blockDim.x + threadIdx.x;   // exact cover of total4
    int b = i / per_img4;
    int hw4 = i & (hw4n - 1);
    int h = hw4 >> 6;                     // hw4 = h*64 + w4
    int w0 = (hw4 & 63) << 2;             // first of 4 consecutive w (4-aligned)
    int hb = h & 63, hwd = h >> 6;

    u64 q0 = masks[(((size_t)0 * BB + b) * 256 + h) * 4 + (w0 >> 6)];
    u64 q1 = masks[(((size_t)1 * BB + b) * 256 + h) * 4 + (w0 >> 6)];
    const u64* c2 = colm + (((size_t)0 * BB + b) * 4 + hwd) * 256 + w0;
    const u64* c3 = colm + (((size_t)1 * BB + b) * 4 + hwd) * 256 + w0;
    u64x2 c2a = *reinterpret_cast<const u64x2*>(c2);
    u64x2 c2b = *reinterpret_cast<const u64x2*>(c2 + 2);
    u64x2 c3a = *reinterpret_cast<const u64x2*>(c3);
    u64x2 c3b = *reinterpret_cast<const u64x2*>(c3 + 2);
    u64 cw2[4] = { c2a.x, c2a.y, c2b.x, c2b.y };
    u64 cw3[4] = { c3a.x, c3a.y, c3b.x, c3b.y };

    f32x4 sv;
#pragma unroll
    for (int k = 0; k < 4; ++k) {
        int wbit = (w0 & 63) + k;
        int v = (int)((q0 >> wbit) & 1ull) + (int)((q1 >> wbit) & 1ull)
              + (int)((cw2[k] >> hb) & 1ull) + (int)((cw3[k] >> hb) & 1ull);
        float fV = (float)v;
        sv[k] = fV / (fV + 1e-6f);
    }
    f32x4 xv = reinterpret_cast<const f32x4*>(x)[i];
    f32x4 ov = xv * sv;
    __builtin_nontemporal_store(ov, reinterpret_cast<f32x4*>(out) + i);
}

extern "C" void kernel_launch(void* const* d_in, const int* in_sizes, int n_in,
                              void* d_out, int out_size, void* d_ws, size_t ws_size,
                              hipStream_t stream) {
    const float* x = (const float*)d_in[0];
    float* out = (float*)d_out;
    char* ws = (char*)d_ws;

    size_t off = 0;
    float* m     = (float*)(ws + off); off += (size_t)2 * 1024 * 1024;      // 2 MB
    float* mag   = (float*)(ws + off); off += (size_t)2 * 1024 * 1024;      // 2 MB
    signed char* adj = (signed char*)(ws + off); off += 524288;             // 512 KB
    u64* masks   = (u64*)(ws + off); off += 131072;                         // 128 KB (dirs 0,1)
    u64* colm    = (u64*)(ws + off); off += 131072;                         // 128 KB (dirs 2,3 transposed)
    float* part  = (float*)(ws + off); off += 16384;                        // 16 KB
    unsigned* mn_u = (unsigned*)(ws + off); off += 64;
    unsigned* mx_u = mn_u + 8;
    unsigned* bar  = (unsigned*)(ws + off); off += 64;                      // 3x {cnt,flag}

    hipMemsetAsync(bar, 0, 6 * sizeof(unsigned), stream);
    k_fused<<<NBLK, 256, 0, stream>>>(x, m, mag, adj, part, masks, colm, mn_u, mx_u, bar);
    k_out<<<(BB * CC * HW / 4) / 256, 256, 0, stream>>>(x, masks, colm, out);
}

// Round 9
// 316.292 us; speedup vs baseline: 1.9658x; 1.9658x over previous
//
#include <hip/hip_runtime.h>
#include <math.h>

#define BB 8
#define CC 96
#define HH 256
#define WW 256
#define HW (HH*WW)

typedef unsigned long long u64;
typedef float f32x4 __attribute__((ext_vector_type(4)));
typedef u64 u64x2 __attribute__((ext_vector_type(2)));

// ---------------- channel mean: x[B,C,H,W] -> m[B,H,W]  (+ init min/max + ticket) ----------------
__global__ void k_mean(const float* __restrict__ x, float* __restrict__ m,
                       unsigned* __restrict__ mn_u, unsigned* __restrict__ mx_u,
                       unsigned* __restrict__ tcnt) {
    if (blockIdx.x == 0) {
        if (threadIdx.x < BB)            mn_u[threadIdx.x] = 0x7f800000u;
        else if (threadIdx.x < 2 * BB)   mx_u[threadIdx.x - BB] = 0u;
        else if (threadIdx.x == 2 * BB)  tcnt[0] = 0u;
    }
    int blk = blockIdx.x;                 // b*256 + tile
    int b = blk >> 8, tile = blk & 255;
    int wv = threadIdx.x >> 6, ln = threadIdx.x & 63;
    int hw4 = tile * 64 + ln;             // float4 index within image
    const int per = HW / 4;               // 16384
    const float4* xb = reinterpret_cast<const float4*>(x)
                     + ((size_t)b * CC + wv * 24) * per + hw4;
    double a0 = 0, a1 = 0, a2 = 0, a3 = 0;
#pragma unroll
    for (int c = 0; c < 24; ++c) {
        float4 v = xb[(size_t)c * per];
        a0 += (double)v.x; a1 += (double)v.y; a2 += (double)v.z; a3 += (double)v.w;
    }
    __shared__ double sbuf[4][4][64];
    sbuf[wv][0][ln] = a0; sbuf[wv][1][ln] = a1;
    sbuf[wv][2][ln] = a2; sbuf[wv][3][ln] = a3;
    __syncthreads();
    if (wv == 0) {
        double r0 = sbuf[0][0][ln] + sbuf[1][0][ln] + sbuf[2][0][ln] + sbuf[3][0][ln];
        double r1 = sbuf[0][1][ln] + sbuf[1][1][ln] + sbuf[2][1][ln] + sbuf[3][1][ln];
        double r2 = sbuf[0][2][ln] + sbuf[1][2][ln] + sbuf[2][2][ln] + sbuf[3][2][ln];
        double r3 = sbuf[0][3][ln] + sbuf[1][3][ln] + sbuf[2][3][ln] + sbuf[3][3][ln];
        float4 o;
        o.x = (float)(r0 / 96.0); o.y = (float)(r1 / 96.0);
        o.z = (float)(r2 / 96.0); o.w = (float)(r3 / 96.0);
        reinterpret_cast<float4*>(m)[(size_t)b * per + hw4] = o;
    }
}

// ---------------- sobel magnitude + per-image min/max ----------------
__global__ void k_sobel(const float* __restrict__ m, float* __restrict__ mag,
                        unsigned* mn_u, unsigned* mx_u) {
    int row = blockIdx.x;            // b*HH + h  (one row per block)
    int b = row >> 8, h = row & 255, w = threadIdx.x;
    const float* mb = m + (size_t)b * HW;
    auto at = [&](int hh, int ww) -> float {
        if (hh < 0 || hh >= HH || ww < 0 || ww >= WW) return 0.0f;
        return mb[hh * WW + ww];
    };
    float a00 = at(h - 1, w - 1), a01 = at(h - 1, w), a02 = at(h - 1, w + 1);
    float a10 = at(h, w - 1),                         a12 = at(h, w + 1);
    float a20 = at(h + 1, w - 1), a21 = at(h + 1, w), a22 = at(h + 1, w + 1);
    float gx = a00 - a02 + 2.0f * a10 - 2.0f * a12 + a20 - a22;
    float gy = a00 + 2.0f * a01 + a02 - a20 - 2.0f * a21 - a22;
    float mg = sqrtf(gx * gx + gy * gy + 1e-6f);
    mag[row * WW + w] = mg;

    float lmn = mg, lmx = mg;
    for (int off = 32; off; off >>= 1) {
        lmn = fminf(lmn, __shfl_down(lmn, off));
        lmx = fmaxf(lmx, __shfl_down(lmx, off));
    }
    __shared__ float smn[4], smx[4];
    int wv = threadIdx.x >> 6, ln = threadIdx.x & 63;
    if (ln == 0) { smn[wv] = lmn; smx[wv] = lmx; }
    __syncthreads();
    if (threadIdx.x == 0) {
        float bmn = fminf(fminf(smn[0], smn[1]), fminf(smn[2], smn[3]));
        float bmx = fmaxf(fmaxf(smx[0], smx[1]), fmaxf(smx[2], smx[3]));
        atomicMin(&mn_u[b], __float_as_uint(bmn));   // mg > 0 -> uint order == float order
        atomicMax(&mx_u[b], __float_as_uint(bmx));
    }
}

// ---------------- fused: normalize -> adj + part, then last-32 blocks run base+traversal ----------------
#define SETBIT(j) do { int _j = (j); \
    if (_j < 64) m0 |= 1ull << _j; \
    else if (_j < 128) m1 |= 1ull << (_j - 64); \
    else if (_j < 192) m2 |= 1ull << (_j - 128); \
    else m3 |= 1ull << (_j - 192); } while (0)

__global__ void k_adjtrav(const float* __restrict__ mag, const unsigned* __restrict__ mn_u,
                          const unsigned* __restrict__ mx_u, signed char* __restrict__ adj,
                          float* __restrict__ part, u64* __restrict__ masks,
                          u64* __restrict__ colm, unsigned* __restrict__ tcnt) {
    const unsigned NB = BB * HH;          // 2048 blocks
    int row = blockIdx.x;                 // b*HH + h
    int b = row >> 8, h = row & 255, w = threadIdx.x;
    float mn = __uint_as_float(mn_u[b]);
    float mx = __uint_as_float(mx_u[b]);
    float rng = mx - mn;
    const float* gb = mag + (size_t)b * HW;
    auto cat = [&](int hh, int ww) -> float {
        if (hh < 0 || hh >= HH || ww < 0 || ww >= WW) return 0.0f;
        float mg = gb[hh * WW + ww];
        return (rng > 0.0f) ? (mg - mn) / (rng + 1e-6f) : 0.0f;
    };
    float cc = cat(h, w);

    float r = cc;
    for (int off = 32; off; off >>= 1) r += __shfl_down(r, off);
    __shared__ float s[4];
    int wv = threadIdx.x >> 6, ln = threadIdx.x & 63;
    if (ln == 0) s[wv] = r;
    __syncthreads();
    if (threadIdx.x == 0) {
        part[row * 2 + 0] = s[0] + s[1];   // w in [0,128)
        part[row * 2 + 1] = s[2] + s[3];   // w in [128,256)
    }

    const float w9 = 1.0f / 9.0f;
    float acc = 0.0f;
    acc = fmaf(cat(h - 1, w - 1), w9, acc);
    acc = fmaf(cat(h - 1, w    ), w9, acc);
    acc = fmaf(cat(h - 1, w + 1), w9, acc);
    acc = fmaf(cat(h    , w - 1), w9, acc);
    acc = fmaf(cc,               w9, acc);
    acc = fmaf(cat(h    , w + 1), w9, acc);
    acc = fmaf(cat(h + 1, w - 1), w9, acc);
    acc = fmaf(cat(h + 1, w    ), w9, acc);
    acc = fmaf(cat(h + 1, w + 1), w9, acc);
    float sg = 1.0f / (1.0f + expf(-5.0f * (acc - 0.5f)));
    adj[row * WW + w] = (signed char)(int)rintf(sg * 2.0f - 1.0f);

    // ---- ticket: last 32 blocks to finish run the traversal ----
    __threadfence();                      // publish adj/part (L2 writeback)
    __syncthreads();
    __shared__ unsigned stkt;
    if (threadIdx.x == 0) stkt = atomicAdd(tcnt, 1u);
    __syncthreads();
    unsigned tkt = stkt;
    if (tkt < NB - 32u) return;

    if (threadIdx.x == 0) {               // wait for all blocks (<=31 stragglers), load-poll
        while (__hip_atomic_load(tcnt, __ATOMIC_RELAXED, __HIP_MEMORY_SCOPE_AGENT) < NB)
            __builtin_amdgcn_s_sleep(1);
    }
    __syncthreads();
    __threadfence();                      // acquire: invalidate stale adj/part

    int unit = (int)(tkt - (NB - 32u));   // 0..31
    int dir = unit >> 3, tb = unit & 7;
    int t = threadIdx.x;

    __shared__ double sd[128];
    __shared__ int sbs;
    int hlo = (dir >> 1) ? 128 : 0;
    int col = dir & 1;
    if (t < 128) sd[t] = (double)part[((tb << 8) + hlo + t) * 2 + col];
    __syncthreads();
    for (int str = 64; str > 0; str >>= 1) {
        if (t < str) sd[t] += sd[t + str];
        __syncthreads();
    }
    if (t == 0) {
        float rc = (float)(sd[0] / 16384.0);
        float sig = 1.0f / (1.0f + expf(-5.0f * (rc - 0.5f)));
        float bsf = 5.0f - sig * 4.0f;
        bsf = fminf(fmaxf(bsf, 1.0f), 5.0f);
        sbs = (int)rintf(bsf);
    }
    __syncthreads();
    int bs = sbs;

    int rr = t;
    const signed char* ab = adj + (size_t)tb * HW;
    u64 m0 = 0, m1 = 0, m2 = 0, m3 = 0;
    if (dir == 0) {
        int j = 0;
        while (j < WW) { SETBIT(j);
            int st = bs + (int)ab[rr * WW + j];
            st = st < 1 ? 1 : (st > 5 ? 5 : st); j += st; }
    } else if (dir == 1) {
        int j = WW - 1;
        while (j >= 0) { SETBIT(j);
            int st = bs + (int)ab[rr * WW + j];
            st = st < 1 ? 1 : (st > 5 ? 5 : st); j -= st; }
    } else if (dir == 2) {
        int j = 0;
        while (j < HH) { SETBIT(j);
            int st = bs + (int)ab[j * WW + rr];
            st = st < 1 ? 1 : (st > 5 ? 5 : st); j += st; }
    } else {
        int j = HH - 1;
        while (j >= 0) { SETBIT(j);
            int st = bs + (int)ab[j * WW + rr];
            st = st < 1 ? 1 : (st > 5 ? 5 : st); j -= st; }
    }
    if (dir < 2) {
        u64* o = masks + (((size_t)dir * BB + tb) * 256 + rr) * 4;
        o[0] = m0; o[1] = m1; o[2] = m2; o[3] = m3;
    } else {
        // transposed: colm[(dir-2)][b][hwd][w] ; lane = w -> coalesced stores
        u64* ct = colm + (((size_t)(dir - 2) * BB + tb) * 4) * 256 + rr;
        ct[0 * 256] = m0; ct[1 * 256] = m1; ct[2 * 256] = m2; ct[3 * 256] = m3;
    }
}

// ---------------- output: one thread per (b,hw4) pixel-quad, loop over 96 channels ----------------
__global__ void k_out(const float* __restrict__ x, const u64* __restrict__ masks,
                      const u64* __restrict__ colm, float* __restrict__ out) {
    const int per = HW / 4;               // 16384 float4 per channel-plane
    int i = blockIdx.x * blockDim.x + threadIdx.x;   // 0..131071 = (b, hw4)
    int b = i >> 14;
    int hw4 = i & (per - 1);
    int h = hw4 >> 6;                     // hw4 = h*64 + w4
    int w0 = (hw4 & 63) << 2;             // first of 4 consecutive w (4-aligned)
    int hb = h & 63, hwd = h >> 6;

    // row-direction masks: one word covers w0..w0+3 (broadcast across 16 lanes)
    u64 q0 = masks[(((size_t)0 * BB + b) * 256 + h) * 4 + (w0 >> 6)];
    u64 q1 = masks[(((size_t)1 * BB + b) * 256 + h) * 4 + (w0 >> 6)];
    // col-direction masks: transposed layout -> 4 consecutive u64, unit-stride across lanes
    const u64* c2 = colm + (((size_t)0 * BB + b) * 4 + hwd) * 256 + w0;
    const u64* c3 = colm + (((size_t)1 * BB + b) * 4 + hwd) * 256 + w0;
    u64x2 c2a = *reinterpret_cast<const u64x2*>(c2);
    u64x2 c2b = *reinterpret_cast<const u64x2*>(c2 + 2);
    u64x2 c3a = *reinterpret_cast<const u64x2*>(c3);
    u64x2 c3b = *reinterpret_cast<const u64x2*>(c3 + 2);
    u64 cw2[4] = { c2a.x, c2a.y, c2b.x, c2b.y };
    u64 cw3[4] = { c3a.x, c3a.y, c3b.x, c3b.y };

    f32x4 sv;
#pragma unroll
    for (int k = 0; k < 4; ++k) {
        int wbit = (w0 & 63) + k;
        int v = (int)((q0 >> wbit) & 1ull) + (int)((q1 >> wbit) & 1ull)
              + (int)((cw2[k] >> hb) & 1ull) + (int)((cw3[k] >> hb) & 1ull);
        float fV = (float)v;
        sv[k] = fV / (fV + 1e-6f);
    }

    const f32x4* xb = reinterpret_cast<const f32x4*>(x) + (size_t)b * CC * per + hw4;
    f32x4* ob = reinterpret_cast<f32x4*>(out) + (size_t)b * CC * per + hw4;
#pragma unroll 4
    for (int c = 0; c < CC; ++c) {
        f32x4 xv = xb[(size_t)c * per];
        __builtin_nontemporal_store(xv * sv, ob + (size_t)c * per);
    }
}

extern "C" void kernel_launch(void* const* d_in, const int* in_sizes, int n_in,
                              void* d_out, int out_size, void* d_ws, size_t ws_size,
                              hipStream_t stream) {
    const float* x = (const float*)d_in[0];
    float* out = (float*)d_out;
    char* ws = (char*)d_ws;

    size_t off = 0;
    float* m     = (float*)(ws + off); off += (size_t)2 * 1024 * 1024;      // 2 MB
    float* mag   = (float*)(ws + off); off += (size_t)2 * 1024 * 1024;      // 2 MB
    signed char* adj = (signed char*)(ws + off); off += 524288;             // 512 KB
    u64* masks   = (u64*)(ws + off); off += 131072;                         // 128 KB (dirs 0,1)
    u64* colm    = (u64*)(ws + off); off += 131072;                         // 128 KB (dirs 2,3 transposed)
    float* part  = (float*)(ws + off); off += 16384;                        // 16 KB
    unsigned* mn_u = (unsigned*)(ws + off); off += 64;
    unsigned* mx_u = mn_u + 8;
    unsigned* tcnt = (unsigned*)(ws + off); off += 64;

    k_mean<<<BB * 256, 256, 0, stream>>>(x, m, mn_u, mx_u, tcnt);
    k_sobel<<<BB * HH, 256, 0, stream>>>(m, mag, mn_u, mx_u);
    k_adjtrav<<<BB * HH, 256, 0, stream>>>(mag, mn_u, mx_u, adj, part, masks, colm, tcnt);
    k_out<<<(BB * HW / 4) / 256, 256, 0, stream>>>(x, masks, colm, out);
}

// Round 10
// 171.903 us; speedup vs baseline: 3.6170x; 1.8399x over previous
//
#include <hip/hip_runtime.h>
#include <math.h>

#define BB 8
#define CC 96
#define HH 256
#define WW 256
#define HW (HH*WW)

typedef unsigned long long u64;
typedef float f32x4 __attribute__((ext_vector_type(4)));
typedef u64 u64x2 __attribute__((ext_vector_type(2)));

// ---------------- channel mean: x[B,C,H,W] -> m[B,H,W]  (+ init min/max) ----------------
__global__ void k_mean(const float* __restrict__ x, float* __restrict__ m,
                       unsigned* __restrict__ mn_u, unsigned* __restrict__ mx_u) {
    if (blockIdx.x == 0 && threadIdx.x < 2 * BB) {
        if (threadIdx.x < BB) mn_u[threadIdx.x] = 0x7f800000u;
        else                  mx_u[threadIdx.x - BB] = 0u;
    }
    int blk = blockIdx.x;                 // b*256 + tile
    int b = blk >> 8, tile = blk & 255;
    int wv = threadIdx.x >> 6, ln = threadIdx.x & 63;
    int hw4 = tile * 64 + ln;             // float4 index within image
    const int per = HW / 4;               // 16384
    const float4* xb = reinterpret_cast<const float4*>(x)
                     + ((size_t)b * CC + wv * 24) * per + hw4;
    double a0 = 0, a1 = 0, a2 = 0, a3 = 0;
#pragma unroll
    for (int c = 0; c < 24; ++c) {
        float4 v = xb[(size_t)c * per];
        a0 += (double)v.x; a1 += (double)v.y; a2 += (double)v.z; a3 += (double)v.w;
    }
    __shared__ double sbuf[4][4][64];
    sbuf[wv][0][ln] = a0; sbuf[wv][1][ln] = a1;
    sbuf[wv][2][ln] = a2; sbuf[wv][3][ln] = a3;
    __syncthreads();
    if (wv == 0) {
        double r0 = sbuf[0][0][ln] + sbuf[1][0][ln] + sbuf[2][0][ln] + sbuf[3][0][ln];
        double r1 = sbuf[0][1][ln] + sbuf[1][1][ln] + sbuf[2][1][ln] + sbuf[3][1][ln];
        double r2 = sbuf[0][2][ln] + sbuf[1][2][ln] + sbuf[2][2][ln] + sbuf[3][2][ln];
        double r3 = sbuf[0][3][ln] + sbuf[1][3][ln] + sbuf[2][3][ln] + sbuf[3][3][ln];
        float4 o;
        o.x = (float)(r0 / 96.0); o.y = (float)(r1 / 96.0);
        o.z = (float)(r2 / 96.0); o.w = (float)(r3 / 96.0);
        reinterpret_cast<float4*>(m)[(size_t)b * per + hw4] = o;
    }
}

// ---------------- sobel magnitude + per-image min/max ----------------
__global__ void k_sobel(const float* __restrict__ m, float* __restrict__ mag,
                        unsigned* mn_u, unsigned* mx_u) {
    int row = blockIdx.x;            // b*HH + h  (one row per block)
    int b = row >> 8, h = row & 255, w = threadIdx.x;
    const float* mb = m + (size_t)b * HW;
    auto at = [&](int hh, int ww) -> float {
        if (hh < 0 || hh >= HH || ww < 0 || ww >= WW) return 0.0f;
        return mb[hh * WW + ww];
    };
    float a00 = at(h - 1, w - 1), a01 = at(h - 1, w), a02 = at(h - 1, w + 1);
    float a10 = at(h, w - 1),                         a12 = at(h, w + 1);
    float a20 = at(h + 1, w - 1), a21 = at(h + 1, w), a22 = at(h + 1, w + 1);
    float gx = a00 - a02 + 2.0f * a10 - 2.0f * a12 + a20 - a22;
    float gy = a00 + 2.0f * a01 + a02 - a20 - 2.0f * a21 - a22;
    float mg = sqrtf(gx * gx + gy * gy + 1e-6f);
    mag[row * WW + w] = mg;

    float lmn = mg, lmx = mg;
    for (int off = 32; off; off >>= 1) {
        lmn = fminf(lmn, __shfl_down(lmn, off));
        lmx = fmaxf(lmx, __shfl_down(lmx, off));
    }
    __shared__ float smn[4], smx[4];
    int wv = threadIdx.x >> 6, ln = threadIdx.x & 63;
    if (ln == 0) { smn[wv] = lmn; smx[wv] = lmx; }
    __syncthreads();
    if (threadIdx.x == 0) {
        float bmn = fminf(fminf(smn[0], smn[1]), fminf(smn[2], smn[3]));
        float bmx = fmaxf(fmaxf(smx[0], smx[1]), fmaxf(smx[2], smx[3]));
        atomicMin(&mn_u[b], __float_as_uint(bmn));   // mg > 0 -> uint order == float order
        atomicMax(&mx_u[b], __float_as_uint(bmx));
    }
}

// ---------------- fused: normalize (recompute per neighbor) -> adj + part ----------------
__global__ void k_adjpart(const float* __restrict__ mag, const unsigned* __restrict__ mn_u,
                          const unsigned* __restrict__ mx_u, signed char* __restrict__ adj,
                          float* __restrict__ part) {
    int row = blockIdx.x;            // b*HH + h
    int b = row >> 8, h = row & 255, w = threadIdx.x;
    float mn = __uint_as_float(mn_u[b]);
    float mx = __uint_as_float(mx_u[b]);
    float rng = mx - mn;
    const float* gb = mag + (size_t)b * HW;
    auto cat = [&](int hh, int ww) -> float {
        if (hh < 0 || hh >= HH || ww < 0 || ww >= WW) return 0.0f;
        float mg = gb[hh * WW + ww];
        return (rng > 0.0f) ? (mg - mn) / (rng + 1e-6f) : 0.0f;
    };
    float cc = cat(h, w);

    float r = cc;
    for (int off = 32; off; off >>= 1) r += __shfl_down(r, off);
    __shared__ float s[4];
    int wv = threadIdx.x >> 6, ln = threadIdx.x & 63;
    if (ln == 0) s[wv] = r;
    __syncthreads();
    if (threadIdx.x == 0) {
        part[row * 2 + 0] = s[0] + s[1];   // w in [0,128)
        part[row * 2 + 1] = s[2] + s[3];   // w in [128,256)
    }

    const float w9 = 1.0f / 9.0f;
    float acc = 0.0f;
    acc = fmaf(cat(h - 1, w - 1), w9, acc);
    acc = fmaf(cat(h - 1, w    ), w9, acc);
    acc = fmaf(cat(h - 1, w + 1), w9, acc);
    acc = fmaf(cat(h    , w - 1), w9, acc);
    acc = fmaf(cc,               w9, acc);
    acc = fmaf(cat(h    , w + 1), w9, acc);
    acc = fmaf(cat(h + 1, w - 1), w9, acc);
    acc = fmaf(cat(h + 1, w    ), w9, acc);
    acc = fmaf(cat(h + 1, w + 1), w9, acc);
    float sg = 1.0f / (1.0f + expf(-5.0f * (acc - 0.5f)));
    adj[row * WW + w] = (signed char)(int)rintf(sg * 2.0f - 1.0f);
}

// ---------------- fused base + traversal -> row-layout masks + transposed col masks ----------------
#define SETBIT(j) do { int _j = (j); \
    if (_j < 64) m0 |= 1ull << _j; \
    else if (_j < 128) m1 |= 1ull << (_j - 64); \
    else if (_j < 192) m2 |= 1ull << (_j - 128); \
    else m3 |= 1ull << (_j - 192); } while (0)

__global__ void k_travbase(const signed char* __restrict__ adj, const float* __restrict__ part,
                           u64* __restrict__ masks, u64* __restrict__ colm) {
    int blk = blockIdx.x;                 // 0..31, = dir*8 + b
    int dir = blk >> 3, b = blk & 7;
    int t = threadIdx.x;

    __shared__ double sd[128];
    __shared__ int sbs;
    int hlo = (dir >> 1) ? 128 : 0;
    int col = dir & 1;
    if (t < 128) sd[t] = (double)part[((b << 8) + hlo + t) * 2 + col];
    __syncthreads();
    for (int str = 64; str > 0; str >>= 1) {
        if (t < str) sd[t] += sd[t + str];
        __syncthreads();
    }
    if (t == 0) {
        float rc = (float)(sd[0] / 16384.0);
        float sig = 1.0f / (1.0f + expf(-5.0f * (rc - 0.5f)));
        float bsf = 5.0f - sig * 4.0f;
        bsf = fminf(fmaxf(bsf, 1.0f), 5.0f);
        sbs = (int)rintf(bsf);
    }
    __syncthreads();
    int bs = sbs;

    int r = t;
    const signed char* ab = adj + (size_t)b * HW;
    u64 m0 = 0, m1 = 0, m2 = 0, m3 = 0;
    if (dir == 0) {
        int j = 0;
        while (j < WW) { SETBIT(j);
            int st = bs + (int)ab[r * WW + j];
            st = st < 1 ? 1 : (st > 5 ? 5 : st); j += st; }
    } else if (dir == 1) {
        int j = WW - 1;
        while (j >= 0) { SETBIT(j);
            int st = bs + (int)ab[r * WW + j];
            st = st < 1 ? 1 : (st > 5 ? 5 : st); j -= st; }
    } else if (dir == 2) {
        int j = 0;
        while (j < HH) { SETBIT(j);
            int st = bs + (int)ab[j * WW + r];
            st = st < 1 ? 1 : (st > 5 ? 5 : st); j += st; }
    } else {
        int j = HH - 1;
        while (j >= 0) { SETBIT(j);
            int st = bs + (int)ab[j * WW + r];
            st = st < 1 ? 1 : (st > 5 ? 5 : st); j -= st; }
    }
    if (dir < 2) {
        u64* o = masks + (((size_t)dir * BB + b) * 256 + r) * 4;
        o[0] = m0; o[1] = m1; o[2] = m2; o[3] = m3;
    } else {
        // transposed: colm[(dir-2)][b][hwd][w] ; lane = w -> coalesced stores
        u64* ct = colm + (((size_t)(dir - 2) * BB + b) * 4) * 256 + r;
        ct[0 * 256] = m0; ct[1 * 256] = m1; ct[2 * 256] = m2; ct[3 * 256] = m3;
    }
}

// ---------------- output: one thread per (b,hw4) pixel-quad, loop over 96 channels ----------------
__global__ void k_out(const float* __restrict__ x, const u64* __restrict__ masks,
                      const u64* __restrict__ colm, float* __restrict__ out) {
    const int per = HW / 4;               // 16384 float4 per channel-plane
    int i = blockIdx.x * blockDim.x + threadIdx.x;   // 0..131071 = (b, hw4)
    int b = i >> 14;
    int hw4 = i & (per - 1);
    int h = hw4 >> 6;                     // hw4 = h*64 + w4
    int w0 = (hw4 & 63) << 2;             // first of 4 consecutive w (4-aligned)
    int hb = h & 63, hwd = h >> 6;

    // row-direction masks: one word covers w0..w0+3 (broadcast across 16 lanes)
    u64 q0 = masks[(((size_t)0 * BB + b) * 256 + h) * 4 + (w0 >> 6)];
    u64 q1 = masks[(((size_t)1 * BB + b) * 256 + h) * 4 + (w0 >> 6)];
    // col-direction masks: transposed layout -> 4 consecutive u64, unit-stride across lanes
    const u64* c2 = colm + (((size_t)0 * BB + b) * 4 + hwd) * 256 + w0;
    const u64* c3 = colm + (((size_t)1 * BB + b) * 4 + hwd) * 256 + w0;
    u64x2 c2a = *reinterpret_cast<const u64x2*>(c2);
    u64x2 c2b = *reinterpret_cast<const u64x2*>(c2 + 2);
    u64x2 c3a = *reinterpret_cast<const u64x2*>(c3);
    u64x2 c3b = *reinterpret_cast<const u64x2*>(c3 + 2);
    u64 cw2[4] = { c2a.x, c2a.y, c2b.x, c2b.y };
    u64 cw3[4] = { c3a.x, c3a.y, c3b.x, c3b.y };

    f32x4 sv;
#pragma unroll
    for (int k = 0; k < 4; ++k) {
        int wbit = (w0 & 63) + k;
        int v = (int)((q0 >> wbit) & 1ull) + (int)((q1 >> wbit) & 1ull)
              + (int)((cw2[k] >> hb) & 1ull) + (int)((cw3[k] >> hb) & 1ull);
        float fV = (float)v;
        sv[k] = fV / (fV + 1e-6f);
    }

    const f32x4* xb = reinterpret_cast<const f32x4*>(x) + (size_t)b * CC * per + hw4;
    f32x4* ob = reinterpret_cast<f32x4*>(out) + (size_t)b * CC * per + hw4;
#pragma unroll 4
    for (int c = 0; c < CC; ++c) {
        f32x4 xv = xb[(size_t)c * per];
        __builtin_nontemporal_store(xv * sv, ob + (size_t)c * per);
    }
}

extern "C" void kernel_launch(void* const* d_in, const int* in_sizes, int n_in,
                              void* d_out, int out_size, void* d_ws, size_t ws_size,
                              hipStream_t stream) {
    const float* x = (const float*)d_in[0];
    float* out = (float*)d_out;
    char* ws = (char*)d_ws;

    size_t off = 0;
    float* m     = (float*)(ws + off); off += (size_t)2 * 1024 * 1024;      // 2 MB
    float* mag   = (float*)(ws + off); off += (size_t)2 * 1024 * 1024;      // 2 MB
    signed char* adj = (signed char*)(ws + off); off += 524288;             // 512 KB
    u64* masks   = (u64*)(ws + off); off += 131072;                         // 128 KB (dirs 0,1)
    u64* colm    = (u64*)(ws + off); off += 131072;                         // 128 KB (dirs 2,3 transposed)
    float* part  = (float*)(ws + off); off += 16384;                        // 16 KB
    unsigned* mn_u = (unsigned*)(ws + off); off += 64;
    unsigned* mx_u = mn_u + 8;

    k_mean<<<BB * 256, 256, 0, stream>>>(x, m, mn_u, mx_u);
    k_sobel<<<BB * HH, 256, 0, stream>>>(m, mag, mn_u, mx_u);
    k_adjpart<<<BB * HH, 256, 0, stream>>>(mag, mn_u, mx_u, adj, part);
    k_travbase<<<32, 256, 0, stream>>>(adj, part, masks, colm);
    k_out<<<(BB * HW / 4) / 256, 256, 0, stream>>>(x, masks, colm, out);
}